// Round 9
// baseline (186.218 us; speedup 1.0000x reference)
//
#include <hip/hip_runtime.h>

#define N_NODES 50000
#define N_EDGES 800000
#define K_BR    8
#define BCAP    131072           // per-bucket slot capacity (2^17); mean fill 100K
#define MLP_SLOTS (K_BR * BCAP)  // 1,048,576
#define SCAN_BLOCKS 196          // ceil(50000/256)
#define BSTRIDE 1024             // bucketCur stride in ints (R1: null, kept)
#define EPT 8                    // pass1 edges/thread (R3 structure)
#define P1_BLOCKS 391            // ceil(800000 / 2048)
#define RB 128                   // rank blocks
#define RBE 6250                 // edges per rank block (128*6250 = 800000 exactly)

// R8 accounting: pipeline ~94us vs harness constant ~92us (two 268MB poison
// fills @42us — immovable). R9: three distributed wins:
//  (1) memset dispatch folded into rank block 0 (8 ints + 196 words).
//  (2) cscan: cntM panel LDS-staged with 4B/lane coalesced loads (was 1B/lane
//      column walk, 128 narrow reads).
//  (3) agg: wave-per-node (was 8 thr/node: wave time = max deg of 8 random
//      nodes ~25 vs mean 16). 4 quarters x 16 ch-pairs, j+=4 loop, 2 shfl_xor.

typedef _Float16 h2 __attribute__((ext_vector_type(2)));
typedef _Float16 half8 __attribute__((ext_vector_type(8)));
typedef float f32x4 __attribute__((ext_vector_type(4)));

#define MFMA(a, b, c) __builtin_amdgcn_mfma_f32_16x16x32_f16((a), (b), (c), 0, 0, 0)

#define VAL_MASK 0x3FFFFFFFu
#define FLG_A    0x40000000u
#define FLG_P    0x80000000u

// ---------------- workspace layout (bytes) ----------------
// fbuf      : 800,000 x 64 B f16         @ 0           (51,200,000)
// payload   : MLP_SLOTS x 16 B           @ 51,200,000  (16,777,216)
// cnt(deg)  : N ints                     @ 67,977,216  (200,000)  [written by cscan]
// bucketCur : 8 ints @ 4KB stride        @ 68,177,216  (32,768)   [zeroed by rank b0]
// ps        : 196 uints (lookback)       @ 68,209,984  (800)      [zeroed by rank b0]
// nodeStart : N ints                     @ 68,210,816  (200,000)
// w1f4      : 2048 uint4 (B-frags L1)    @ 68,410,816  (32,768)
// w2f4      : 1024 uint4 (B-frags L2)    @ 68,443,584  (16,384)
// xh        : 50,000 x 32 f16            @ 68,459,968  (3,200,000)
// rankB     : E u16 (rank within block)  @ 71,659,968  (1,600,000)
// cntM      : [128][50000] u8            @ 73,259,968  (6,400,000)
// blkBase   : [128][50000] u16           @ 86,059,968  (12,800,000)
// total: 98,859,968

__device__ __forceinline__ int branch_idx(float dx, float dy) {
    return (dx > 0.0f ? 1 : 0) + (dy > 0.0f ? 2 : 0) +
           ((fabsf(dx) - fabsf(dy)) > 0.0f ? 4 : 0);
}

__device__ __forceinline__ unsigned pk_f16pair(float a, float b) {
    h2 p; p.x = (_Float16)a; p.y = (_Float16)b;
    return __builtin_bit_cast(unsigned, p);
}

__device__ __forceinline__ unsigned short f16bits(float a) {
    _Float16 h = (_Float16)a;
    return __builtin_bit_cast(unsigned short, h);
}

// Per-block node histogram + per-edge rank, NO device atomics.
// LDS: 12,500 u32 = four u8 counters per word. 512 threads/block.
// Also absorbs x->f16 mirror, W-frag packing, and bucketCur/ps zeroing (b0).
__global__ void __launch_bounds__(512) rank_kernel(
    const int* __restrict__ ei, const float* __restrict__ x,
    const float* __restrict__ W1, const float* __restrict__ W2,
    unsigned short* __restrict__ rankB, unsigned char* __restrict__ cntM,
    unsigned* __restrict__ xh, uint4* __restrict__ w1f4, uint4* __restrict__ w2f4,
    int* __restrict__ bucketCur, unsigned* __restrict__ ps) {
    __shared__ unsigned hist[N_NODES / 4];   // 50,000 B
    int t = threadIdx.x, b = blockIdx.x;
    for (int i = t; i < N_NODES / 4; i += 512) hist[i] = 0;

    if (b == 0) {                            // absorbed memset
        if (t < K_BR) bucketCur[t * BSTRIDE] = 0;
        if (t < SCAN_BLOCKS) ps[t] = 0;
    }

    // W fragments (global tid < 3072)
    int tid = b * 512 + t;
    if (tid < 2048) {                         // layer-1 B frags
        int L = tid & 63, fl = tid >> 6;
        int nt = fl & 1, kt = (fl >> 1) & 1, k = fl >> 2;
        int quad = L >> 4, col = L & 15;
        unsigned dw[4];
#pragma unroll
        for (int i = 0; i < 4; ++i) {
            float v0 = 0.0f, v1 = 0.0f;
            int k0 = kt * 32 + quad * 8 + 2 * i;
            if (k0 < 36)     v0 = W1[k * 1152 + k0 * 32 + nt * 16 + col];
            if (k0 + 1 < 36) v1 = W1[k * 1152 + (k0 + 1) * 32 + nt * 16 + col];
            dw[i] = pk_f16pair(v0, v1);
        }
        w1f4[tid] = make_uint4(dw[0], dw[1], dw[2], dw[3]);
    } else if (tid < 3072) {                  // layer-2 B frags
        int u2 = tid - 2048;
        int L = u2 & 63, fl = u2 >> 6;
        int nt = fl & 1, k = fl >> 1;
        int quad = L >> 4, col = L & 15;
        unsigned dw[4];
#pragma unroll
        for (int i = 0; i < 4; ++i) {
            int k0 = quad * 8 + 2 * i;
            dw[i] = pk_f16pair(W2[k * 1024 + k0 * 32 + nt * 16 + col],
                               W2[k * 1024 + (k0 + 1) * 32 + nt * 16 + col]);
        }
        w2f4[u2] = make_uint4(dw[0], dw[1], dw[2], dw[3]);
    }

    __syncthreads();
    int eb = b * RBE;
    for (int it = 0; it < (RBE + 511) / 512; ++it) {
        int r = it * 512 + t;
        if (r < RBE) {
            int e = eb + r;
            int d = ei[N_EDGES + e];
            unsigned sh = (unsigned)(d & 3) * 8u;
            unsigned old = atomicAdd(&hist[d >> 2], 1u << sh);
            rankB[e] = (unsigned short)((old >> sh) & 0xFFu);
            // x mirror: e covers all 800K float2 of x exactly once
            float2 xv = ((const float2*)x)[e];
            xh[e] = pk_f16pair(xv.x, xv.y);
        }
    }
    __syncthreads();
    // dump histogram row as u32 words (4 nodes per word)
    unsigned* cm = (unsigned*)(cntM + (size_t)b * N_NODES);
    for (int i = t; i < N_NODES / 4; i += 512) cm[i] = hist[i];
}

// Fused per-node column-scan (over RB blocks) + decoupled-lookback exclusive
// scan over nodes. R9: cntM panel staged in LDS via coalesced 4B/lane loads.
__global__ void cscan_kernel(const unsigned char* __restrict__ cntM,
                             unsigned short* __restrict__ blkBase,
                             int* __restrict__ cnt, unsigned* __restrict__ ps,
                             int* __restrict__ nodeStart) {
    __shared__ unsigned char cmLds[RB * 256];  // 32,768 B
    __shared__ int s[256];
    __shared__ int sh_off;
    int t = threadIdx.x, b = blockIdx.x;
    int d0 = b * 256;
    int d = d0 + t;
    // stage panel: rows 0..127, 256 bytes each (reads may overrun row end by
    // <=252B on the last block; stays inside workspace, values masked below)
#pragma unroll
    for (int it = 0; it < RB / 4; ++it) {
        int i = it * 256 + t;                // [0, 8192)
        int row = i >> 6;                    // 64 u32 per 256B row
        int w = i & 63;
        ((unsigned*)cmLds)[row * 64 + w] =
            *(const unsigned*)(cntM + (size_t)row * N_NODES + d0 + (w << 2));
    }
    __syncthreads();
    int acc = 0;
    if (d < N_NODES) {
#pragma unroll 8
        for (int blk = 0; blk < RB; ++blk) {
            int v = cmLds[blk * 256 + t];
            blkBase[(size_t)blk * N_NODES + d] = (unsigned short)acc;
            acc += v;
        }
        cnt[d] = acc;
    }
    int v = (d < N_NODES) ? acc : 0;
    s[t] = v;
    __syncthreads();
#pragma unroll
    for (int off = 1; off < 256; off <<= 1) {
        int tmp = (t >= off) ? s[t - off] : 0;
        __syncthreads();
        s[t] += tmp;
        __syncthreads();
    }
    int excl = s[t] - v;
    if (t == 255)
        atomicExch(&ps[b], (unsigned)s[255] | (b == 0 ? FLG_P : FLG_A));
    if (t == 0) sh_off = 0;
    if (t < 64 && b > 0) {   // wave-parallel lookback in wave 0
        int off = 0;
        int base = b - 1;
        for (;;) {
            int idx = base - t;
            unsigned w = 0;
            if (idx >= 0) {
                do { w = atomicOr(&ps[idx], 0u); } while (!(w & (FLG_A | FLG_P)));
            }
            bool isP = (w & FLG_P) != 0;
            unsigned long long pm = __ballot(isP);
            int firstP = pm ? (__ffsll((unsigned long long)pm) - 1) : 64;
            int contrib = (idx >= 0 && t <= firstP) ? (int)(w & VAL_MASK) : 0;
#pragma unroll
            for (int sh = 32; sh > 0; sh >>= 1) contrib += __shfl_down(contrib, sh, 64);
            contrib = __shfl(contrib, 0, 64);
            off += contrib;
            if (firstP < 64 || base - 64 < 0) break;
            base -= 64;
        }
        if (t == 0) sh_off = off;
    }
    __syncthreads();
    if (d < N_NODES) nodeStart[d] = excl + sh_off;
}

// Edge pass: branch histogram + bucket scatter of packed 16B payload.
// slotLocal = blkBase[e/RBE][d] + rankB[e]  (no device atomics).
__global__ void pass1_kernel(const int* __restrict__ ei, const float* __restrict__ pos,
                             const float* __restrict__ ea, const float* __restrict__ ew,
                             const unsigned short* __restrict__ rankB,
                             const unsigned short* __restrict__ blkBase,
                             int* __restrict__ bucketCur,
                             uint4* __restrict__ payload) {
    __shared__ int h[K_BR];
    __shared__ int base[K_BR];
    int t = threadIdx.x;
    if (t < K_BR) h[t] = 0;
    __syncthreads();

    int eBase = blockIdx.x * (256 * EPT);
    int sA[EPT], dA[EPT], krA[EPT], slA[EPT];
#pragma unroll
    for (int it = 0; it < EPT; ++it) {
        int e = eBase + it * 256 + t;        // coalesced per sub-iteration
        int s = 0, d = 0, k = 0, rank = 0, slot = 0;
        if (e < N_EDGES) {
            s = ei[e]; d = ei[N_EDGES + e];
            float2 ps2 = ((const float2*)pos)[s];
            float2 pd2 = ((const float2*)pos)[d];
            k = branch_idx(ps2.x - pd2.x, ps2.y - pd2.y);
            rank = atomicAdd(&h[k], 1);
            int bb = e / RBE;
            slot = (int)blkBase[(size_t)bb * N_NODES + d] + (int)rankB[e];
        }
        sA[it] = s; dA[it] = d; krA[it] = (k << 16) | rank; slA[it] = slot;
    }
    __syncthreads();
    if (t < K_BR) base[t] = (h[t] > 0) ? atomicAdd(&bucketCur[t * BSTRIDE], h[t]) : 0;
    __syncthreads();
#pragma unroll
    for (int it = 0; it < EPT; ++it) {
        int e = eBase + it * 256 + t;
        if (e < N_EDGES) {
            int k = krA[it] >> 16, rank = krA[it] & 0xFFFF;
            float4 eav = ((const float4*)ea)[e];
            unsigned ewh = (unsigned)f16bits(ew[e]);
            int idx = (k << 17) + base[k] + rank;
            payload[idx] = make_uint4((unsigned)sA[it] | ((unsigned)dA[it] << 16),
                                      (unsigned)slA[it] | (ewh << 16),
                                      pk_f16pair(eav.x, eav.y),
                                      pk_f16pair(eav.z, eav.w));
        }
    }
}

// R7 MFMA MLP: no m/out LDS staging. A-frags gathered straight from xh in MFMA
// layout (owner lane's s/d/ea via __shfl); outputs stored straight from the
// accumulators (owner's slot/wh/valid via __shfl). LDS = h-transpose only.
__global__ void __launch_bounds__(128, 4) mlp_kernel(
    const uint4* __restrict__ payload,
    const unsigned* __restrict__ xh,
    const uint4* __restrict__ w1f4, const float* __restrict__ b1,
    const uint4* __restrict__ w2f4, const float* __restrict__ b2,
    const int* __restrict__ nodeStart,
    const int* __restrict__ bucketFill,
    unsigned short* __restrict__ fbuf) {
    __shared__ uint4 lds4[164];              // 2,624 B = 2 x (1280 + 32 pad)
    char* hreg = (char*)lds4 + (threadIdx.x >> 6) * 1312;

    int t = blockIdx.x * 128 + threadIdx.x;
    int u = __builtin_amdgcn_readfirstlane(t);
    int k = u >> 17;
    int fill = bucketFill[k * BSTRIDE];
    if ((u & (BCAP - 1)) >= fill) return;   // whole wave past bucket fill
    int rel = t & (BCAP - 1);
    bool valid = rel < fill;
    int idx = (k << 17) + min(rel, fill - 1);  // clamp: pad slots are garbage

    int L = threadIdx.x & 63;
    int quad = L >> 4, col = L & 15;

    uint4 pl = payload[idx];
    int s = (int)(pl.x & 0xFFFFu);
    int d = (int)(pl.x >> 16);
    float whf = (float)__builtin_bit_cast(_Float16, (unsigned short)(pl.y >> 16));
    int slot = valid ? (nodeStart[d] + (int)(pl.y & 0xFFFFu)) : 0;
    int vld = valid ? 1 : 0;

    // ---- B fragments (held in VGPRs; coalesced 16B/lane loads) ----
    half8 B1[2][2], B2[2];
#pragma unroll
    for (int kt = 0; kt < 2; ++kt)
#pragma unroll
        for (int nt = 0; nt < 2; ++nt)
            B1[kt][nt] = __builtin_bit_cast(half8, w1f4[((k * 2 + kt) * 2 + nt) * 64 + L]);
#pragma unroll
    for (int nt = 0; nt < 2; ++nt)
        B2[nt] = __builtin_bit_cast(half8, w2f4[(k * 2 + nt) * 64 + L]);
    float b1o0 = b1[k * 32 + col],      b1o1 = b1[k * 32 + 16 + col];
    float b2o0 = b2[k * 32 + col],      b2o1 = b2[k * 32 + 16 + col];

#pragma unroll
    for (int mt = 0; mt < 4; ++mt) {
        // ---- A-frag: lane (quad,col) holds row er=mt*16+col, k=quad*8..+8 ----
        int erA = mt * 16 + col;
        int sA = __shfl(s, erA, 64);
        int dAi = __shfl(d, erA, 64);
        unsigned zA = (unsigned)__shfl((int)pl.z, erA, 64);
        unsigned wA = (unsigned)__shfl((int)pl.w, erA, 64);
        uint4 xjv = ((const uint4*)xh)[4 * (size_t)sA + quad];
        uint4 xiv = ((const uint4*)xh)[4 * (size_t)dAi + quad];
        half8 a0 = __builtin_bit_cast(half8, xjv) - __builtin_bit_cast(half8, xiv);
        uint4 a1u = make_uint4(quad == 0 ? zA : 0u, quad == 0 ? wA : 0u, 0u, 0u);
        half8 a1 = __builtin_bit_cast(half8, a1u);

        f32x4 c0 = {b1o0, b1o0, b1o0, b1o0};
        f32x4 c1 = {b1o1, b1o1, b1o1, b1o1};
        c0 = MFMA(a0, B1[0][0], c0);
        c0 = MFMA(a1, B1[1][0], c0);
        c1 = MFMA(a0, B1[0][1], c1);
        c1 = MFMA(a1, B1[1][1], c1);
        // ReLU -> h transpose buffer (16 edges x 32 ch f16); wave-synchronous
#pragma unroll
        for (int r = 0; r < 4; ++r) {
            int er = quad * 4 + r;
            *(unsigned short*)(hreg + er * 80 + col * 2)        = f16bits(fmaxf(c0[r], 0.0f));
            *(unsigned short*)(hreg + er * 80 + (16 + col) * 2) = f16bits(fmaxf(c1[r], 0.0f));
        }
        // layer 2
        half8 ah = __builtin_bit_cast(half8, *(const uint4*)(hreg + col * 80 + quad * 16));
        f32x4 d0 = {b2o0, b2o0, b2o0, b2o0};
        f32x4 d1 = {b2o1, b2o1, b2o1, b2o1};
        d0 = MFMA(ah, B2[0], d0);
        d1 = MFMA(ah, B2[1], d1);
        // ---- direct store: lane holds ch col / col+16 of edge mt*16+quad*4+r ----
#pragma unroll
        for (int r = 0; r < 4; ++r) {
            int erC = mt * 16 + quad * 4 + r;
            int slC = __shfl(slot, erC, 64);
            float wC = __shfl(whf, erC, 64);
            int vC = __shfl(vld, erC, 64);
            unsigned short v0 = f16bits(fmaxf(d0[r], 0.0f) * wC);
            unsigned short v1 = f16bits(fmaxf(d1[r], 0.0f) * wC);
            if (vC) {
                unsigned short* orow = fbuf + 32 * (size_t)slC;
                orow[col] = v0;
                orow[16 + col] = v1;
            }
        }
    }
}

// R9 agg: ONE WAVE PER NODE. 4 lane-quarters x 16 channel-pairs; edge loop
// j += 4 (mean 4 iters, zero inter-node divergence); 2x shfl_xor reduce;
// skip-GEMM split across quarters; coalesced float2 store from quarter 0.
__global__ void agg_kernel(const unsigned short* __restrict__ fbuf,
                           const int* __restrict__ nodeStart, const int* __restrict__ deg,
                           const float* __restrict__ x, const float* __restrict__ Wr,
                           const float* __restrict__ br, float* __restrict__ out) {
    int gw = (blockIdx.x * blockDim.x + threadIdx.x) >> 6;   // wave id = node
    if (gw >= N_NODES) return;
    int l = threadIdx.x & 63;
    int q = l >> 4, cp = l & 15;         // quarter, channel pair -> ch 2cp,2cp+1
    int st = nodeStart[gw], dg = deg[gw];
    float a0 = 0.0f, a1 = 0.0f;
    for (int j = q; j < dg; j += 4) {
        unsigned uu = *(const unsigned*)(fbuf + (size_t)(st + j) * 32 + 2 * cp);
        h2 p = __builtin_bit_cast(h2, uu);
        a0 += (float)p.x;
        a1 += (float)p.y;
    }
    float inv = 1.0f / (float)max(dg, 1);
    int c0 = 2 * cp;
    float p0 = a0 * inv + (q == 0 ? br[c0] : 0.0f);
    float p1 = a1 * inv + (q == 0 ? br[c0 + 1] : 0.0f);
    const float* xr = x + 32 * (size_t)gw + q * 8;
#pragma unroll
    for (int kk = 0; kk < 8; ++kk) {
        float xv = xr[kk];
        p0 = fmaf(xv, Wr[(q * 8 + kk) * 32 + c0], p0);
        p1 = fmaf(xv, Wr[(q * 8 + kk) * 32 + c0 + 1], p1);
    }
    p0 += __shfl_xor(p0, 16, 64);
    p0 += __shfl_xor(p0, 32, 64);
    p1 += __shfl_xor(p1, 16, 64);
    p1 += __shfl_xor(p1, 32, 64);
    if (q == 0) {
        float2 o = make_float2(p0, p1);
        *(float2*)(out + 32 * (size_t)gw + c0) = o;
    }
}

extern "C" void kernel_launch(void* const* d_in, const int* in_sizes, int n_in,
                              void* d_out, int out_size, void* d_ws, size_t ws_size,
                              hipStream_t stream) {
    const float* x   = (const float*)d_in[0];
    const float* pos = (const float*)d_in[1];
    const int*   ei  = (const int*)d_in[2];
    const float* ea  = (const float*)d_in[3];
    const float* ew  = (const float*)d_in[4];
    const float* W1  = (const float*)d_in[5];
    const float* b1  = (const float*)d_in[6];
    const float* W2  = (const float*)d_in[7];
    const float* b2  = (const float*)d_in[8];
    const float* Wr  = (const float*)d_in[9];
    const float* br  = (const float*)d_in[10];
    float* out = (float*)d_out;

    char* ws = (char*)d_ws;
    unsigned short* fbuf = (unsigned short*)(ws + 0);
    uint4* payload  = (uint4*)(ws + 51200000);
    int* cnt        = (int*)(ws + 67977216);
    int* bucketCur  = (int*)(ws + 68177216);   // 8 counters @ 4KB stride
    unsigned* psLb  = (unsigned*)(ws + 68209984);
    int* nodeStart  = (int*)(ws + 68210816);
    uint4* w1f4     = (uint4*)(ws + 68410816);
    uint4* w2f4     = (uint4*)(ws + 68443584);
    unsigned* xh    = (unsigned*)(ws + 68459968);
    unsigned short* rankB = (unsigned short*)(ws + 71659968);
    unsigned char* cntM   = (unsigned char*)(ws + 73259968);
    unsigned short* blkBase = (unsigned short*)(ws + 86059968);

    rank_kernel<<<RB, 512, 0, stream>>>(ei, x, W1, W2, rankB, cntM, xh, w1f4, w2f4,
                                        bucketCur, psLb);
    cscan_kernel<<<SCAN_BLOCKS, 256, 0, stream>>>(cntM, blkBase, cnt, psLb, nodeStart);
    pass1_kernel<<<P1_BLOCKS, 256, 0, stream>>>(ei, pos, ea, ew, rankB, blkBase,
                                                bucketCur, payload);
    mlp_kernel<<<MLP_SLOTS / 128, 128, 0, stream>>>(payload, xh, w1f4, b1, w2f4, b2,
                                                    nodeStart, bucketCur, fbuf);
    agg_kernel<<<(N_NODES * 64) / 256, 256, 0, stream>>>(fbuf, nodeStart, cnt,
                                                         x, Wr, br, out);
}